// Round 9
// baseline (113.483 us; speedup 1.0000x reference)
//
#include <hip/hip_runtime.h>
#include <cstddef>

// YOLOv3 loss, MI355X. b=32, scales 13/26/52, 3 anchors, 80 classes, 50 boxes.
// Input order (setup_inputs dict order, interleaved per scale):
//   d_in[4k+0]=output_k (b,255,S,S)  d_in[4k+1]=loc_k (b,3,4,S,S)
//   d_in[4k+2]=cls_k (b,3,80,S,S)    d_in[4k+3]=boxes_k (b,50,4)
// ws: 4 doubles {LL, LC, LK, NPOS}
//
// R8 = R4 body (best ~60us) + __launch_bounds__(256,1) + explicit A/B depth-2
// pipeline. R4's VGPR=76 proved the compiler never kept 16 loads in flight
// (it minimized regs for occupancy the grid can't use anyway: 384 blocks =
// 1.5 waves/SIMD). (256,1) frees up to 256 VGPR so the 32-outstanding-float4
// pipeline (128 VGPR of buffers) can actually materialize.

constexpr int NC = 80;
constexpr int NA = 3;
constexpr int NM = 50;
constexpr int NB = 32;

__device__ constexpr float ANCW[3][3] = {{116.f,156.f,373.f},{30.f,62.f,59.f},{10.f,16.f,33.f}};
__device__ constexpr float ANCH[3][3] = {{ 90.f,198.f,326.f},{61.f,45.f,119.f},{13.f,30.f,23.f}};

__device__ __forceinline__ float frcp_(float x) { return __builtin_amdgcn_rcpf(x); }
__device__ __forceinline__ float sigmoidf_(float x) { return frcp_(1.0f + __expf(-x)); }

template <int VW>
__device__ __forceinline__ void loadv(const float* __restrict__ p, float (&d)[VW]) {
    if constexpr (VW == 4) {
        const float4 v = *reinterpret_cast<const float4*>(p);
        d[0] = v.x; d[1] = v.y; d[2] = v.z; d[3] = v.w;
    } else {
        d[0] = p[0];
    }
}

__global__ void init_acc_kernel(double* acc) {
    if (threadIdx.x < 4) acc[threadIdx.x] = 0.0;
}

__global__ void finalize_kernel(const double* __restrict__ acc, float* __restrict__ out) {
    out[0] = (float)(5.0 * (acc[0] + acc[1] + acc[2]) / (double)NB / acc[3]);
}

template <int SC, int S, int VW, bool COUNT_POS>
__device__ __forceinline__ void process_scale(
    const float* __restrict__ outp, const float* __restrict__ locp,
    const float* __restrict__ clsp, const float* __restrict__ boxp,
    double* __restrict__ acc, int rel)
{
    constexpr int SS = S * S;
    constexpr int CELLS = NA * SS;
    constexpr int CPB = 256 * VW;
    constexpr int BPB = (CELLS + CPB - 1) / CPB;

    const int b   = rel / BPB;
    const int chk = rel % BPB;
    const int tid = threadIdx.x;

    __shared__ float4 sbx4[NM];
    __shared__ float  sba[NM];
    __shared__ float  red[4][4];

    if (tid < NM) {
        const float4 bb = *reinterpret_cast<const float4*>(boxp + (size_t)b * NM * 4 + tid * 4);
        sbx4[tid] = bb;
        sba[tid]  = (bb.z - bb.x) * (bb.w - bb.y);
    }

    float ll = 0.f, lc = 0.f, lk = 0.f, np = 0.f;

    const int cell0 = (chk * 256 + tid) * VW;
    const bool active = cell0 < CELLS;

    float Z[VW] = {}, A2[VW] = {}, A1[VW] = {}, A0[VW] = {};
    float tx[VW], ty[VW], tw[VW], th[VW], tc[VW];
    float l0[VW], l1[VW], l2[VW], l3[VW];
    int a = 0, rem = 0;

    if (active) {
        a   = cell0 / SS;
        rem = cell0 - a * SS;

        const float* op  = outp + ((size_t)b * NA + a) * (5 + NC) * SS + rem;
        const float* cp  = clsp + ((size_t)b * NA + a) * NC * SS + rem;
        const float* lp  = locp + ((size_t)b * NA + a) * 4 * SS + rem;
        const float* opc = op + (size_t)5 * SS;

        // tail loads first: in flight under the class loop
        loadv<VW>(op + 0 * SS, tx);
        loadv<VW>(op + 1 * SS, ty);
        loadv<VW>(op + 2 * SS, tw);
        loadv<VW>(op + 3 * SS, th);
        loadv<VW>(op + 4 * SS, tc);
        loadv<VW>(lp + 0 * SS, l0);
        loadv<VW>(lp + 1 * SS, l1);
        loadv<VW>(lp + 2 * SS, l2);
        loadv<VW>(lp + 3 * SS, l3);

        // class loss: sum_{t>0}(p-t)^2 = A2/Z^2 - 2 A1/Z + A0
        // explicit depth-2 pipeline: two 16-load batches (A/B) in flight.
        float LbA[8][VW], TbA[8][VW], LbB[8][VW], TbB[8][VW];

#define ISSUE_BATCH(c0, LB, TB)                                              \
        do {                                                                 \
            _Pragma("unroll")                                                \
            for (int j = 0; j < 8; ++j)                                      \
                loadv<VW>(opc + (size_t)((c0) + j) * SS, LB[j]);             \
            _Pragma("unroll")                                                \
            for (int j = 0; j < 8; ++j)                                      \
                loadv<VW>(cp + (size_t)((c0) + j) * SS, TB[j]);              \
        } while (0)

#define CONSUME_BATCH(LB, TB)                                                \
        do {                                                                 \
            _Pragma("unroll")                                                \
            for (int j = 0; j < 8; ++j) {                                    \
                _Pragma("unroll")                                            \
                for (int i = 0; i < VW; ++i) {                               \
                    const float e = __expf(LB[j][i]);                        \
                    const float t = TB[j][i];                                \
                    const float u = fmaxf(t, 0.f);                           \
                    const float we = (t > 0.f) ? e : 0.f;                    \
                    Z[i] += e;                                               \
                    A2[i] = fmaf(we, e, A2[i]);                              \
                    A1[i] = fmaf(we, t, A1[i]);                              \
                    A0[i] = fmaf(u,  t, A0[i]);                              \
                }                                                            \
            }                                                                \
        } while (0)

        ISSUE_BATCH(0,  LbA, TbA);
        ISSUE_BATCH(8,  LbB, TbB);
        CONSUME_BATCH(LbA, TbA); ISSUE_BATCH(16, LbA, TbA);
        CONSUME_BATCH(LbB, TbB); ISSUE_BATCH(24, LbB, TbB);
        CONSUME_BATCH(LbA, TbA); ISSUE_BATCH(32, LbA, TbA);
        CONSUME_BATCH(LbB, TbB); ISSUE_BATCH(40, LbB, TbB);
        CONSUME_BATCH(LbA, TbA); ISSUE_BATCH(48, LbA, TbA);
        CONSUME_BATCH(LbB, TbB); ISSUE_BATCH(56, LbB, TbB);
        CONSUME_BATCH(LbA, TbA); ISSUE_BATCH(64, LbA, TbA);
        CONSUME_BATCH(LbB, TbB); ISSUE_BATCH(72, LbB, TbB);
        CONSUME_BATCH(LbA, TbA);
        CONSUME_BATCH(LbB, TbB);
#undef ISSUE_BATCH
#undef CONSUME_BATCH
    }

    __syncthreads();   // sbx4/sba ready; hidden under the class loop

    if (active) {
        const float aw = ANCW[SC][a] * ((float)S / 416.f);
        const float ah = ANCH[SC][a] * ((float)S / 416.f);

        float x1[VW], y1[VW], x2[VW], y2[VW], area[VW], bn[VW], bd[VW];
        bool pos[VW];
        #pragma unroll
        for (int i = 0; i < VW; ++i) {
            pos[i] = A0[i] > 0.f;
            const float d0 = tx[i]-l0[i], d1 = ty[i]-l1[i], d2 = tw[i]-l2[i], d3 = th[i]-l3[i];
            const float lli = d0*d0 + d1*d1 + d2*d2 + d3*d3;
            ll += pos[i] ? lli : 0.f;
            if (COUNT_POS) np += pos[i] ? 1.f : 0.f;

            const int ri = rem + i;
            const int y  = ri / S;
            const int x  = ri - y * S;
            const float sx = sigmoidf_(tx[i]) + (float)x;
            const float sy = sigmoidf_(ty[i]) + (float)y;
            const float bw = __expf(tw[i]) * aw;
            const float bh = __expf(th[i]) * ah;
            x1[i] = sx - bw * 0.5f;  y1[i] = sy - bh * 0.5f;
            x2[i] = sx + bw * 0.5f;  y2[i] = sy + bh * 0.5f;
            area[i] = (x2[i] - x1[i]) * (y2[i] - y1[i]);
            bn[i] = 0.f; bd[i] = 1.f;
        }

        // max IoU vs 50 boxes, rational compare (single rcp at end)
        for (int j = 0; j < NM; ++j) {
            const float4 bb = sbx4[j];
            const float ab  = sba[j];
            #pragma unroll
            for (int i = 0; i < VW; ++i) {
                const float iw = fmaxf(fminf(x2[i], bb.z) - fmaxf(x1[i], bb.x), 0.f);
                const float ih = fmaxf(fminf(y2[i], bb.w) - fmaxf(y1[i], bb.y), 0.f);
                const float inter = iw * ih;
                const float uni   = area[i] + ab - inter;
                const bool upd = inter * bd[i] > bn[i] * uni;
                bn[i] = upd ? inter : bn[i];
                bd[i] = upd ? uni   : bd[i];
            }
        }

        #pragma unroll
        for (int i = 0; i < VW; ++i) {
            const float best  = bn[i] * frcp_(bd[i]);
            const float cpred = sigmoidf_(tc[i]);
            const float m2    = pos[i] ? 1.f : 0.01f;
            const float d     = cpred - best;
            lc += m2 * d * d;
            const float invZ = frcp_(Z[i]);
            lk += fmaf(A2[i] * invZ, invZ, fmaf(-2.f * A1[i], invZ, A0[i]));
        }
    }

    // block reduction
    for (int off = 32; off > 0; off >>= 1) {
        ll += __shfl_down(ll, off);
        lc += __shfl_down(lc, off);
        lk += __shfl_down(lk, off);
        if (COUNT_POS) np += __shfl_down(np, off);
    }
    const int wave = tid >> 6, lane = tid & 63;
    if (lane == 0) { red[wave][0]=ll; red[wave][1]=lc; red[wave][2]=lk; red[wave][3]=np; }
    __syncthreads();
    if (tid == 0) {
        float s0=0, s1=0, s2=0, s3=0;
        for (int w = 0; w < 4; ++w) { s0+=red[w][0]; s1+=red[w][1]; s2+=red[w][2]; s3+=red[w][3]; }
        atomicAdd(&acc[0], (double)s0);
        atomicAdd(&acc[1], (double)s1);
        atomicAdd(&acc[2], (double)s2);
        if (COUNT_POS) atomicAdd(&acc[3], (double)s3);
    }
}

// block ranges: S=52 VW4 -> 256 blocks; S=26 VW4 -> 64; S=13 VW1 -> 64
constexpr int NBLK2 = NB * ((NA*52*52 + 1023) / 1024);   // 256
constexpr int NBLK1 = NB * ((NA*26*26 + 1023) / 1024);   // 64
constexpr int NBLK0 = NB * ((NA*13*13 + 255) / 256);     // 64

__global__ __launch_bounds__(256, 1) void yolo_all_kernel(
    const float* __restrict__ o0, const float* __restrict__ lo0, const float* __restrict__ c0, const float* __restrict__ bx0,
    const float* __restrict__ o1, const float* __restrict__ lo1, const float* __restrict__ c1, const float* __restrict__ bx1,
    const float* __restrict__ o2, const float* __restrict__ lo2, const float* __restrict__ c2, const float* __restrict__ bx2,
    double* __restrict__ acc)
{
    const int bid = blockIdx.x;
    if (bid < NBLK2) {
        process_scale<2, 52, 4, false>(o2, lo2, c2, bx2, acc, bid);
    } else if (bid < NBLK2 + NBLK1) {
        process_scale<1, 26, 4, false>(o1, lo1, c1, bx1, acc, bid - NBLK2);
    } else {
        process_scale<0, 13, 1, true>(o0, lo0, c0, bx0, acc, bid - NBLK2 - NBLK1);
    }
}

extern "C" void kernel_launch(void* const* d_in, const int* in_sizes, int n_in,
                              void* d_out, int out_size, void* d_ws, size_t ws_size,
                              hipStream_t stream) {
    (void)in_sizes; (void)n_in; (void)out_size; (void)ws_size;
    const float* o0  = (const float*)d_in[0];
    const float* lo0 = (const float*)d_in[1];
    const float* c0  = (const float*)d_in[2];
    const float* bx0 = (const float*)d_in[3];
    const float* o1  = (const float*)d_in[4];
    const float* lo1 = (const float*)d_in[5];
    const float* c1  = (const float*)d_in[6];
    const float* bx1 = (const float*)d_in[7];
    const float* o2  = (const float*)d_in[8];
    const float* lo2 = (const float*)d_in[9];
    const float* c2  = (const float*)d_in[10];
    const float* bx2 = (const float*)d_in[11];

    double* acc = (double*)d_ws;
    float* out = (float*)d_out;

    init_acc_kernel<<<1, 64, 0, stream>>>(acc);
    yolo_all_kernel<<<NBLK2 + NBLK1 + NBLK0, 256, 0, stream>>>(
        o0, lo0, c0, bx0, o1, lo1, c1, bx1, o2, lo2, c2, bx2, acc);
    finalize_kernel<<<1, 1, 0, stream>>>(acc, out);
}

// Round 10
// 65.037 us; speedup vs baseline: 1.7449x; 1.7449x over previous
//
#include <hip/hip_runtime.h>
#include <cstddef>

// YOLOv3 loss, MI355X. b=32, scales 13/26/52, 3 anchors, 80 classes, 50 boxes.
// Input order (setup_inputs dict order, interleaved per scale):
//   d_in[4k+0]=output_k (b,255,S,S)  d_in[4k+1]=loc_k (b,3,4,S,S)
//   d_in[4k+2]=cls_k (b,3,80,S,S)    d_in[4k+3]=boxes_k (b,50,4)
// ws: double acc[32][2] = {T=ll+lc+lk, NPOS} banked by bid%32.
//
// R9: same R4 body (best measured), but:
//  - 64-thread (1-wave) blocks -> 1536 fine-grained equal units (~6/CU):
//    smooth makespan instead of R1's 2 ragged 256-block rounds.
//  - ll/lc/lk share the same 5.0 weight -> fold into ONE accumulator T;
//    atomics banked 32-way by bid%32 (kills same-line atomic serialization).
//  - no launch-bounds min-waves (R8 spill lesson), wave-only reduction.

constexpr int NC = 80;
constexpr int NA = 3;
constexpr int NM = 50;
constexpr int NB = 32;
constexpr int BANKS = 32;

__device__ constexpr float ANCW[3][3] = {{116.f,156.f,373.f},{30.f,62.f,59.f},{10.f,16.f,33.f}};
__device__ constexpr float ANCH[3][3] = {{ 90.f,198.f,326.f},{61.f,45.f,119.f},{13.f,30.f,23.f}};

__device__ __forceinline__ float frcp_(float x) { return __builtin_amdgcn_rcpf(x); }
__device__ __forceinline__ float sigmoidf_(float x) { return frcp_(1.0f + __expf(-x)); }

template <int VW>
__device__ __forceinline__ void loadv(const float* __restrict__ p, float (&d)[VW]) {
    if constexpr (VW == 4) {
        const float4 v = *reinterpret_cast<const float4*>(p);
        d[0] = v.x; d[1] = v.y; d[2] = v.z; d[3] = v.w;
    } else {
        d[0] = p[0];
    }
}

__global__ void init_acc_kernel(double* acc) {
    if (threadIdx.x < BANKS * 2) acc[threadIdx.x] = 0.0;
}

__global__ void finalize_kernel(const double* __restrict__ acc, float* __restrict__ out) {
    double t = 0.0, np = 0.0;
    for (int i = 0; i < BANKS; ++i) { t += acc[i*2+0]; np += acc[i*2+1]; }
    out[0] = (float)(5.0 * t / (double)NB / np);
}

template <int SC, int S, int VW, bool COUNT_POS>
__device__ __forceinline__ void process_scale(
    const float* __restrict__ outp, const float* __restrict__ locp,
    const float* __restrict__ clsp, const float* __restrict__ boxp,
    double* __restrict__ acc, int rel, int bank)
{
    constexpr int SS = S * S;
    constexpr int CELLS = NA * SS;
    constexpr int CPB = 64 * VW;                       // cells per 1-wave block
    constexpr int BPB = (CELLS + CPB - 1) / CPB;

    const int b   = rel / BPB;
    const int chk = rel % BPB;
    const int tid = threadIdx.x;                       // 0..63

    __shared__ float4 sbx4[NM];
    __shared__ float  sba[NM];

    if (tid < NM) {
        const float4 bb = *reinterpret_cast<const float4*>(boxp + (size_t)b * NM * 4 + tid * 4);
        sbx4[tid] = bb;
        sba[tid]  = (bb.z - bb.x) * (bb.w - bb.y);
    }

    float tsum = 0.f, np = 0.f;

    const int cell0 = (chk * 64 + tid) * VW;
    const bool active = cell0 < CELLS;

    float Z[VW] = {}, A2[VW] = {}, A1[VW] = {}, A0[VW] = {};
    float tx[VW], ty[VW], tw[VW], th[VW], tc[VW];
    float l0[VW], l1[VW], l2[VW], l3[VW];
    int a = 0, rem = 0;

    if (active) {
        a   = cell0 / SS;
        rem = cell0 - a * SS;

        const float* op  = outp + ((size_t)b * NA + a) * (5 + NC) * SS + rem;
        const float* cp  = clsp + ((size_t)b * NA + a) * NC * SS + rem;
        const float* lp  = locp + ((size_t)b * NA + a) * 4 * SS + rem;
        const float* opc = op + (size_t)5 * SS;

        // tail loads first: in flight under the class loop
        loadv<VW>(op + 0 * SS, tx);
        loadv<VW>(op + 1 * SS, ty);
        loadv<VW>(op + 2 * SS, tw);
        loadv<VW>(op + 3 * SS, th);
        loadv<VW>(op + 4 * SS, tc);
        loadv<VW>(lp + 0 * SS, l0);
        loadv<VW>(lp + 1 * SS, l1);
        loadv<VW>(lp + 2 * SS, l2);
        loadv<VW>(lp + 3 * SS, l3);

        // class loss: sum_{t>0}(p-t)^2 = A2/Z^2 - 2 A1/Z + A0
        #pragma unroll 2
        for (int c0 = 0; c0 < NC; c0 += 8) {
            float L[8][VW], T[8][VW];
            #pragma unroll
            for (int j = 0; j < 8; ++j)
                loadv<VW>(opc + (size_t)(c0 + j) * SS, L[j]);
            #pragma unroll
            for (int j = 0; j < 8; ++j)
                loadv<VW>(cp + (size_t)(c0 + j) * SS, T[j]);
            #pragma unroll
            for (int j = 0; j < 8; ++j) {
                #pragma unroll
                for (int i = 0; i < VW; ++i) {
                    const float e = __expf(L[j][i]);
                    const float t = T[j][i];
                    const float u = fmaxf(t, 0.f);
                    const float we = (t > 0.f) ? e : 0.f;
                    Z[i] += e;
                    A2[i] = fmaf(we, e, A2[i]);
                    A1[i] = fmaf(we, t, A1[i]);
                    A0[i] = fmaf(u,  t, A0[i]);
                }
            }
        }
    }

    __syncthreads();   // 1-wave block: compiles to a cheap waitcnt

    if (active) {
        const float aw = ANCW[SC][a] * ((float)S / 416.f);
        const float ah = ANCH[SC][a] * ((float)S / 416.f);

        float x1[VW], y1[VW], x2[VW], y2[VW], area[VW], bn[VW], bd[VW];
        bool pos[VW];
        #pragma unroll
        for (int i = 0; i < VW; ++i) {
            pos[i] = A0[i] > 0.f;
            const float d0 = tx[i]-l0[i], d1 = ty[i]-l1[i], d2 = tw[i]-l2[i], d3 = th[i]-l3[i];
            const float lli = d0*d0 + d1*d1 + d2*d2 + d3*d3;
            tsum += pos[i] ? lli : 0.f;
            if (COUNT_POS) np += pos[i] ? 1.f : 0.f;

            const int ri = rem + i;
            const int y  = ri / S;
            const int x  = ri - y * S;
            const float sx = sigmoidf_(tx[i]) + (float)x;
            const float sy = sigmoidf_(ty[i]) + (float)y;
            const float bw = __expf(tw[i]) * aw;
            const float bh = __expf(th[i]) * ah;
            x1[i] = sx - bw * 0.5f;  y1[i] = sy - bh * 0.5f;
            x2[i] = sx + bw * 0.5f;  y2[i] = sy + bh * 0.5f;
            area[i] = (x2[i] - x1[i]) * (y2[i] - y1[i]);
            bn[i] = 0.f; bd[i] = 1.f;
        }

        // max IoU vs 50 boxes, rational compare (single rcp at end)
        for (int j = 0; j < NM; ++j) {
            const float4 bb = sbx4[j];
            const float ab  = sba[j];
            #pragma unroll
            for (int i = 0; i < VW; ++i) {
                const float iw = fmaxf(fminf(x2[i], bb.z) - fmaxf(x1[i], bb.x), 0.f);
                const float ih = fmaxf(fminf(y2[i], bb.w) - fmaxf(y1[i], bb.y), 0.f);
                const float inter = iw * ih;
                const float uni   = area[i] + ab - inter;
                const bool upd = inter * bd[i] > bn[i] * uni;
                bn[i] = upd ? inter : bn[i];
                bd[i] = upd ? uni   : bd[i];
            }
        }

        #pragma unroll
        for (int i = 0; i < VW; ++i) {
            const float best  = bn[i] * frcp_(bd[i]);
            const float cpred = sigmoidf_(tc[i]);
            const float m2    = pos[i] ? 1.f : 0.01f;
            const float d     = cpred - best;
            tsum += m2 * d * d;
            const float invZ = frcp_(Z[i]);
            tsum += fmaf(A2[i] * invZ, invZ, fmaf(-2.f * A1[i], invZ, A0[i]));
        }
    }

    // wave reduction + banked atomics
    for (int off = 32; off > 0; off >>= 1) {
        tsum += __shfl_down(tsum, off);
        if (COUNT_POS) np += __shfl_down(np, off);
    }
    if (tid == 0) {
        atomicAdd(&acc[bank*2+0], (double)tsum);
        if (COUNT_POS) atomicAdd(&acc[bank*2+1], (double)np);
    }
}

// 1-wave blocks: S52: 32 chunks/img -> 1024; S26: 8 -> 256; S13 (VW1): 8 -> 256
constexpr int NBLK2 = NB * ((NA*52*52 + 255) / 256);   // 1024
constexpr int NBLK1 = NB * ((NA*26*26 + 255) / 256);   // 256
constexpr int NBLK0 = NB * ((NA*13*13 + 63) / 64);     // 256
constexpr int TOTAL = NBLK2 + NBLK1 + NBLK0;           // 1536

__global__ __launch_bounds__(64) void yolo_all_kernel(
    const float* __restrict__ o0, const float* __restrict__ lo0, const float* __restrict__ c0, const float* __restrict__ bx0,
    const float* __restrict__ o1, const float* __restrict__ lo1, const float* __restrict__ c1, const float* __restrict__ bx1,
    const float* __restrict__ o2, const float* __restrict__ lo2, const float* __restrict__ c2, const float* __restrict__ bx2,
    double* __restrict__ acc)
{
    const int bid  = blockIdx.x;
    const int bank = bid & (BANKS - 1);
    if (bid < NBLK2) {
        process_scale<2, 52, 4, false>(o2, lo2, c2, bx2, acc, bid, bank);
    } else if (bid < NBLK2 + NBLK1) {
        process_scale<1, 26, 4, false>(o1, lo1, c1, bx1, acc, bid - NBLK2, bank);
    } else {
        process_scale<0, 13, 1, true>(o0, lo0, c0, bx0, acc, bid - NBLK2 - NBLK1, bank);
    }
}

extern "C" void kernel_launch(void* const* d_in, const int* in_sizes, int n_in,
                              void* d_out, int out_size, void* d_ws, size_t ws_size,
                              hipStream_t stream) {
    (void)in_sizes; (void)n_in; (void)out_size; (void)ws_size;
    const float* o0  = (const float*)d_in[0];
    const float* lo0 = (const float*)d_in[1];
    const float* c0  = (const float*)d_in[2];
    const float* bx0 = (const float*)d_in[3];
    const float* o1  = (const float*)d_in[4];
    const float* lo1 = (const float*)d_in[5];
    const float* c1  = (const float*)d_in[6];
    const float* bx1 = (const float*)d_in[7];
    const float* o2  = (const float*)d_in[8];
    const float* lo2 = (const float*)d_in[9];
    const float* c2  = (const float*)d_in[10];
    const float* bx2 = (const float*)d_in[11];

    double* acc = (double*)d_ws;
    float* out = (float*)d_out;

    init_acc_kernel<<<1, 64, 0, stream>>>(acc);
    yolo_all_kernel<<<TOTAL, 64, 0, stream>>>(
        o0, lo0, c0, bx0, o1, lo1, c1, bx1, o2, lo2, c2, bx2, acc);
    finalize_kernel<<<1, 1, 0, stream>>>(acc, out);
}